// Round 1
// baseline (37609.738 us; speedup 1.0000x reference)
//
#include <hip/hip_runtime.h>
#include <hip/hip_cooperative_groups.h>
#include <math.h>

namespace cg = cooperative_groups;

#define SEQ  512
#define NB   64
#define DIN  256
#define HID  512
#define NOUT 128

// ws (float4) layout:
// [0,8192)      h0 parity0   (h[j/4][b], float4 packs j..j+3)
// [8192,16384)  h0 parity1
// [16384,24576) h1 parity0
// [24576,32768) h1 parity1

extern __shared__ float lds[];

__global__ void __launch_bounds__(256, 1)
lstm_wavefront(const float* __restrict__ x,
               const float* __restrict__ Wih0, const float* __restrict__ Whh0,
               const float* __restrict__ bih0, const float* __restrict__ bhh0,
               const float* __restrict__ Wih1, const float* __restrict__ Whh1,
               const float* __restrict__ bih1, const float* __restrict__ bhh1,
               const float* __restrict__ Wy,  const float* __restrict__ by,
               float* __restrict__ out, float4* __restrict__ ws)
{
    const int wg    = blockIdx.x;     // 0..255
    const int tid   = threadIdx.x;    // 0..255
    const int layer = wg >> 7;        // 0: blocks 0..127, 1: blocks 128..255
    const int j0    = (wg & 127) * 4; // 4 hidden units per WG
    const int b     = tid & 63;       // batch lane
    const int q     = tid >> 6;       // gate-type / wave index (0..3)

    float4* h0buf0 = ws;
    float4* h0buf1 = ws + 8192;
    float4* h1buf0 = ws + 16384;
    float4* h1buf1 = ws + 24576;

    const int    KX = layer ? HID : DIN;
    const float* Wx = layer ? Wih1 : Wih0;
    const float* Wh = layer ? Whh1 : Whh0;
    const float* bi = layer ? bih1 : bih0;
    const float* bh = layer ? bhh1 : bhh0;

    // LDS carve (fixed offsets sized for the larger layer): total 70720 B
    float* WxL    = lds;               // [KX][16]  k-major, rows r = 4*type+jj
    float* WhL    = WxL + 512 * 16;    // [512][16]
    float* biasL  = WhL + 512 * 16;    // [16]
    float* gatesL = biasL + 16;        // [16][64]
    float* hxL    = gatesL + 16 * 64;  // [4][64]

    // ---- stage weight slices to LDS (k-major so row-quads are contiguous) ----
    for (int r = 0; r < 16; ++r) {
        const int type = r >> 2, jj = r & 3;
        const int grow = type * HID + j0 + jj;     // global gate row
        const float* srcx = Wx + (size_t)grow * KX;
        for (int k = tid; k < KX; k += 256) WxL[k * 16 + r] = srcx[k];
        const float* srch = Wh + (size_t)grow * HID;
        for (int k = tid; k < HID; k += 256) WhL[k * 16 + r] = srch[k];
    }
    if (tid < 16) {
        const int type = tid >> 2, jj = tid & 3;
        const int grow = type * HID + j0 + jj;
        biasL[tid] = bi[grow] + bh[grow];
    }

    // ---- zero the parity-0 state buffers (ws is poisoned every call) ----
    {
        const int g = wg * 256 + tid;
        const float4 z = make_float4(0.f, 0.f, 0.f, 0.f);
        if (g < 8192)        h0buf0[g] = z;
        else if (g < 16384)  h1buf0[g - 8192] = z;
    }
    float c_state = 0.0f;

    __syncthreads();
    cg::this_grid().sync();

    // ---- wavefront loop: iter it => layer0 does step it, layer1 does step it-1 ----
    for (int it = 0; it <= SEQ; ++it) {
        const bool active = layer ? (it >= 1) : (it < SEQ);
        if (active) {
            float a0 = biasL[q * 4 + 0];
            float a1 = biasL[q * 4 + 1];
            float a2 = biasL[q * 4 + 2];
            float a3 = biasL[q * 4 + 3];

            // ---- input GEMM ----
            if (layer == 0) {
                const float4* xin = (const float4*)(x + ((size_t)b * SEQ + it) * DIN);
                #pragma unroll 4
                for (int k4 = 0; k4 < DIN / 4; ++k4) {
                    const float4 u = xin[k4];
                    #pragma unroll
                    for (int i = 0; i < 4; ++i) {
                        const float4 w = *(const float4*)&WxL[(k4 * 4 + i) * 16 + q * 4];
                        const float ui = (&u.x)[i];
                        a0 += w.x * ui; a1 += w.y * ui; a2 += w.z * ui; a3 += w.w * ui;
                    }
                }
            } else {
                const float4* uin = (it & 1) ? h0buf1 : h0buf0;  // h0[t-1]
                #pragma unroll 4
                for (int k4 = 0; k4 < HID / 4; ++k4) {
                    const float4 u = uin[k4 * 64 + b];
                    #pragma unroll
                    for (int i = 0; i < 4; ++i) {
                        const float4 w = *(const float4*)&WxL[(k4 * 4 + i) * 16 + q * 4];
                        const float ui = (&u.x)[i];
                        a0 += w.x * ui; a1 += w.y * ui; a2 += w.z * ui; a3 += w.w * ui;
                    }
                }
            }

            // ---- recurrent GEMM ----
            const float4* hst;
            if (layer == 0) hst = (it & 1) ? h0buf1 : h0buf0;            // own state
            else            hst = ((it - 1) & 1) ? h1buf1 : h1buf0;      // own state
            #pragma unroll 4
            for (int k4 = 0; k4 < HID / 4; ++k4) {
                const float4 u = hst[k4 * 64 + b];
                #pragma unroll
                for (int i = 0; i < 4; ++i) {
                    const float4 w = *(const float4*)&WhL[(k4 * 4 + i) * 16 + q * 4];
                    const float ui = (&u.x)[i];
                    a0 += w.x * ui; a1 += w.y * ui; a2 += w.z * ui; a3 += w.w * ui;
                }
            }

            gatesL[(q * 4 + 0) * 64 + b] = a0;
            gatesL[(q * 4 + 1) * 64 + b] = a1;
            gatesL[(q * 4 + 2) * 64 + b] = a2;
            gatesL[(q * 4 + 3) * 64 + b] = a3;
        }
        __syncthreads();

        if (active) {
            // rows: r = 4*type + jj ; this thread handles jj = q, batch b
            const float i_g = gatesL[(0  + q) * 64 + b];
            const float f_g = gatesL[(4  + q) * 64 + b];
            const float g_g = gatesL[(8  + q) * 64 + b];
            const float o_g = gatesL[(12 + q) * 64 + b];
            const float ig = 1.f / (1.f + __expf(-i_g));
            const float fg = 1.f / (1.f + __expf(-f_g));
            const float gg = tanhf(g_g);
            const float og = 1.f / (1.f + __expf(-o_g));
            c_state = fg * c_state + ig * gg;
            const float hnew = og * tanhf(c_state);
            hxL[q * 64 + b] = hnew;
        }
        __syncthreads();

        if (active && q == 0) {
            const float4 hv = make_float4(hxL[b], hxL[64 + b], hxL[128 + b], hxL[192 + b]);
            float4* wr;
            if (layer == 0) wr = (it & 1) ? h0buf0 : h0buf1;   // write parity (it&1)^1
            else            wr = (it & 1) ? h1buf1 : h1buf0;   // write parity it&1
            wr[(j0 >> 2) * 64 + b] = hv;
        }
        __threadfence();
        cg::this_grid().sync();
    }

    // ---- output projection: out[b][o] = sum_j h1_final[j][b] * Wy[o][j] + by[o] ----
    // final h1 written at it=SEQ with parity SEQ&1 = 0 -> h1buf0
    const int g = wg * 256 + tid;
    if (g < NB * NOUT) {
        const int o  = g >> 6;   // 0..127  (wave-uniform -> Wy reads broadcast)
        const int bb = g & 63;   // lane -> coalesced h reads
        float acc = by[o];
        const float4* wrow = (const float4*)(Wy + (size_t)o * HID);
        #pragma unroll 4
        for (int j4 = 0; j4 < HID / 4; ++j4) {
            const float4 h = h1buf0[j4 * 64 + bb];
            const float4 w = wrow[j4];
            acc += h.x * w.x + h.y * w.y + h.z * w.z + h.w * w.w;
        }
        out[bb * NOUT + o] = acc;
    }
}

extern "C" void kernel_launch(void* const* d_in, const int* in_sizes, int n_in,
                              void* d_out, int out_size, void* d_ws, size_t ws_size,
                              hipStream_t stream)
{
    const float* x    = (const float*)d_in[0];
    const float* Wih0 = (const float*)d_in[1];
    const float* Whh0 = (const float*)d_in[2];
    const float* bih0 = (const float*)d_in[3];
    const float* bhh0 = (const float*)d_in[4];
    const float* Wih1 = (const float*)d_in[5];
    const float* Whh1 = (const float*)d_in[6];
    const float* bih1 = (const float*)d_in[7];
    const float* bhh1 = (const float*)d_in[8];
    const float* Wy   = (const float*)d_in[9];
    const float* by   = (const float*)d_in[10];
    float*  out = (float*)d_out;
    float4* ws  = (float4*)d_ws;

    (void)in_sizes; (void)n_in; (void)out_size; (void)ws_size;

    // 70720 B dynamic LDS (> 64 KB default cap)
    hipFuncSetAttribute((const void*)lstm_wavefront,
                        hipFuncAttributeMaxDynamicSharedMemorySize, 70720);

    void* args[] = { (void*)&x, (void*)&Wih0, (void*)&Whh0, (void*)&bih0, (void*)&bhh0,
                     (void*)&Wih1, (void*)&Whh1, (void*)&bih1, (void*)&bhh1,
                     (void*)&Wy, (void*)&by, (void*)&out, (void*)&ws };
    hipLaunchCooperativeKernel((const void*)lstm_wavefront, dim3(256), dim3(256),
                               args, 70720, stream);
}

// Round 2
// 17400.027 us; speedup vs baseline: 2.1615x; 2.1615x over previous
//
#include <hip/hip_runtime.h>
#include <hip/hip_cooperative_groups.h>
#include <math.h>

namespace cg = cooperative_groups;

typedef _Float16 f16x8 __attribute__((ext_vector_type(8)));
typedef float    f32x4 __attribute__((ext_vector_type(4)));

#define SEQ   512
#define NB    64
#define DIN   256
#define HID   512
#define NOUT  128

#define L0_NKS 24            // K = 256 (x) + 512 (h0) = 768 -> 24 k-slices of 32
#define L1_NKS 32            // K = 512 (h0) + 512 (h1) = 1024 -> 32 k-slices
#define L0_FRAGS (128 * L0_NKS)   // 3072 A-fragments (128 g-tiles)
#define L1_FRAGS (128 * L1_NKS)   // 4096
#define WA_U4 ((L0_FRAGS + L1_FRAGS) * 64)   // uint4 count of packed-weight area
#define G_U4  4096           // one h-buffer parity: [64 k8][64 b] uint4 (fp16x8) = 64KB

union U4H8 { uint4 u; f16x8 h; };

__device__ __forceinline__ f16x8 asH(uint4 v) { U4H8 c; c.u = v; return c.h; }

__device__ __forceinline__ f16x8 pack8(float4 a, float4 b) {
    f16x8 r;
    r[0] = (_Float16)a.x; r[1] = (_Float16)a.y; r[2] = (_Float16)a.z; r[3] = (_Float16)a.w;
    r[4] = (_Float16)b.x; r[5] = (_Float16)b.y; r[6] = (_Float16)b.z; r[7] = (_Float16)b.w;
    return r;
}

// Persistent-weight sequential loop. Wave q (of 8): type = q&3 (i,f,g,o), btg = q>>2.
// Each wave: one 16-gate tile, FULL K in registers, 2 b-tiles (16 batch each).
template<int LAYER>
__device__ __forceinline__ void run_loop(
    const float* __restrict__ x, const float* __restrict__ bi, const float* __restrict__ bh,
    const uint4* __restrict__ WA, uint4* __restrict__ G0, uint4* __restrict__ G1,
    float (*gsum)[64], int u, int lane, int q)
{
    constexpr int NKS = LAYER ? L1_NKS : L0_NKS;
    const int typ = q & 3, btg = q >> 2;
    const int gt  = typ * 32 + u;                      // global 16-gate tile index
    const long fbase = LAYER ? (long)L0_FRAGS + (long)gt * L1_NKS : (long)gt * L0_NKS;

    // ---- load persistent A fragments (weights) into registers ----
    f16x8 A[NKS];
#pragma unroll
    for (int ks = 0; ks < NKS; ++ks) A[ks] = asH(WA[(fbase + ks) * 64 + lane]);

    // ---- bias (per-lane 4 rows of this wave's D tiles) ----
    const int g0r = typ * 512 + u * 16 + ((lane >> 4) << 2);
    f32x4 bias4;
    {
        const float4 a = *(const float4*)&bi[g0r];
        const float4 b = *(const float4*)&bh[g0r];
        bias4[0] = a.x + b.x; bias4[1] = a.y + b.y; bias4[2] = a.z + b.z; bias4[3] = a.w + b.w;
    }

    // pointwise identity: this thread handles units ju and ju+8 for batch bb
    const int ju = q, bb = lane;
    float cA = 0.f, cB = 0.f;

    cg::grid_group grid = cg::this_grid();

    for (int it = 0; it <= SEQ; ++it) {
        const bool active = LAYER ? (it >= 1) : (it < SEQ);
        if (active) {
            const int t = LAYER ? it - 1 : it;
            const uint4* srcRec = (LAYER ? G1 : G0) + G_U4 * ((t + 1) & 1);  // own h[t-1]
            const uint4* srcIn  = LAYER ? (G0 + G_U4 * (t & 1)) : nullptr;   // h0[t] for layer 1

            f32x4 acc0 = {0.f, 0.f, 0.f, 0.f}, acc1 = {0.f, 0.f, 0.f, 0.f};
#pragma unroll
            for (int ks = 0; ks < NKS; ++ks) {
                f16x8 B0, B1;
                if (LAYER == 0 && ks < 8) {
                    // x region: on-the-fly fp32 -> fp16 fragment build
                    const int k8 = ks * 4 + (lane >> 4);
                    const int b0 = btg * 32 + (lane & 15);
                    const float* xp0 = x + (size_t)b0 * (SEQ * DIN) + (size_t)t * DIN + k8 * 8;
                    const float* xp1 = xp0 + (size_t)16 * (SEQ * DIN);
                    B0 = pack8(*(const float4*)xp0, *(const float4*)(xp0 + 4));
                    B1 = pack8(*(const float4*)xp1, *(const float4*)(xp1 + 4));
                } else {
                    const uint4* Gs; int k8;
                    if (LAYER == 1) {
                        if (ks < 16) { Gs = srcIn;  k8 = ks * 4 + (lane >> 4); }
                        else         { Gs = srcRec; k8 = (ks - 16) * 4 + (lane >> 4); }
                    } else {
                        Gs = srcRec; k8 = (ks - 8) * 4 + (lane >> 4);
                    }
                    B0 = asH(Gs[k8 * 64 + btg * 32 + (lane & 15)]);
                    B1 = asH(Gs[k8 * 64 + btg * 32 + 16 + (lane & 15)]);
                }
                acc0 = __builtin_amdgcn_mfma_f32_16x16x32_f16(A[ks], B0, acc0, 0, 0, 0);
                acc1 = __builtin_amdgcn_mfma_f32_16x16x32_f16(A[ks], B1, acc1, 0, 0, 0);
            }
            // D tile -> LDS gates: row = (lane>>4)*4 + r, col = lane&15
            const int gl   = typ * 16 + ((lane >> 4) << 2);
            const int bcol = btg * 32 + (lane & 15);
#pragma unroll
            for (int r = 0; r < 4; ++r) {
                gsum[gl + r][bcol]      = acc0[r] + bias4[r];
                gsum[gl + r][bcol + 16] = acc1[r] + bias4[r];
            }
        }
        __syncthreads();
        if (active) {
            const int t = LAYER ? it - 1 : it;
            uint4* Gw = (LAYER ? G1 : G0) + G_U4 * (t & 1);
            _Float16* hp = (_Float16*)Gw;
            // unit ju
            {
                const float gi = gsum[ju][bb],      gf = gsum[16 + ju][bb];
                const float gc = gsum[32 + ju][bb], go = gsum[48 + ju][bb];
                const float i_ = 1.f / (1.f + __expf(-gi));
                const float f_ = 1.f / (1.f + __expf(-gf));
                const float g_ = tanhf(gc);
                const float o_ = 1.f / (1.f + __expf(-go));
                cA = f_ * cA + i_ * g_;
                const float h_ = o_ * tanhf(cA);
                const int J = u * 16 + ju;
                hp[((J >> 3) * 64 + bb) * 8 + (J & 7)] = (_Float16)h_;
            }
            // unit ju+8
            {
                const float gi = gsum[ju + 8][bb],      gf = gsum[16 + ju + 8][bb];
                const float gc = gsum[32 + ju + 8][bb], go = gsum[48 + ju + 8][bb];
                const float i_ = 1.f / (1.f + __expf(-gi));
                const float f_ = 1.f / (1.f + __expf(-gf));
                const float g_ = tanhf(gc);
                const float o_ = 1.f / (1.f + __expf(-go));
                cB = f_ * cB + i_ * g_;
                const float h_ = o_ * tanhf(cB);
                const int J = u * 16 + ju + 8;
                hp[((J >> 3) * 64 + bb) * 8 + (J & 7)] = (_Float16)h_;
            }
        }
        __threadfence();
        grid.sync();
    }
}

__global__ void __launch_bounds__(512, 2)
lstm_mfma(const float* __restrict__ x,
          const float* __restrict__ Wih0, const float* __restrict__ Whh0,
          const float* __restrict__ bih0, const float* __restrict__ bhh0,
          const float* __restrict__ Wih1, const float* __restrict__ Whh1,
          const float* __restrict__ bih1, const float* __restrict__ bhh1,
          const float* __restrict__ Wy,  const float* __restrict__ by,
          float* __restrict__ out, uint4* __restrict__ ws)
{
    const int bid  = blockIdx.x;     // 0..63
    const int tid  = threadIdx.x;    // 0..511
    const int lane = tid & 63;
    const int q    = tid >> 6;       // wave 0..7
    const int layer = bid >> 5;
    const int u     = bid & 31;      // 16-unit group within layer

    uint4* WA = ws;
    uint4* G0 = ws + WA_U4;              // [2][4096] uint4  (h0 parities)
    uint4* G1 = G0 + 2 * G_U4;           // [2][4096] uint4  (h1 parities)

    __shared__ float gsum[64][64];
    __shared__ float part[8][64];

    cg::grid_group grid = cg::this_grid();

    // ---------- phase 1: pack weights into fp16 MFMA A-fragments ----------
    for (int task = bid * 512 + tid; task < (L0_FRAGS + L1_FRAGS) * 64; task += 64 * 512) {
        const int f = task >> 6, l = task & 63;
        int g, k;
        const float* src;
        if (f < L0_FRAGS) {
            const int gt = f / L0_NKS;
            const int ks = f - gt * L0_NKS;
            g = gt * 16 + (l & 15);
            k = ks * 32 + (l >> 4) * 8;
            src = (k < DIN) ? (Wih0 + (size_t)g * DIN + k)
                            : (Whh0 + (size_t)g * HID + (k - DIN));
        } else {
            const int f1 = f - L0_FRAGS;
            const int gt = f1 >> 5;
            const int ks = f1 & 31;
            g = gt * 16 + (l & 15);
            k = ks * 32 + (l >> 4) * 8;
            src = (k < HID) ? (Wih1 + (size_t)g * HID + k)
                            : (Whh1 + (size_t)g * HID + (k - HID));
        }
        U4H8 c;
        c.h = pack8(*(const float4*)src, *(const float4*)(src + 4));
        WA[task] = c.u;
    }
    // zero parity-1 h buffers (initial h state = 0); ws is poisoned each call
    {
        const int i = bid * 512 + tid;
        const uint4 z = make_uint4(0u, 0u, 0u, 0u);
        if (i < G_U4)            G0[G_U4 + i] = z;
        else if (i < 2 * G_U4)   G1[G_U4 + (i - G_U4)] = z;
    }
    grid.sync();

    // ---------- phase 2: wavefront-pipelined sequential LSTM ----------
    if (layer == 0) run_loop<0>(x, bih0, bhh0, WA, G0, G1, gsum, u, lane, q);
    else            run_loop<1>(x, bih1, bhh1, WA, G0, G1, gsum, u, lane, q);

    // ---------- phase 3: fused output projection ----------
    // h2_final = h1[511] lives in G1 parity 1 (fp16 G-layout). out[b][o] = h2 . Wy[o] + by[o]
    {
        const uint4* Hf = G1 + G_U4;       // parity 1
        const int osel = q & 1, kq = q >> 1;   // 4-way K split across waves
        const int o = bid * 2 + osel;
        float accE = 0.f;
#pragma unroll
        for (int i = 0; i < 16; ++i) {
            const int k8 = kq * 16 + i;
            const f16x8 h8 = asH(Hf[k8 * 64 + lane]);
            const float4 w0 = *(const float4*)&Wy[(size_t)o * HID + k8 * 8];
            const float4 w1 = *(const float4*)&Wy[(size_t)o * HID + k8 * 8 + 4];
            accE += (float)h8[0] * w0.x + (float)h8[1] * w0.y + (float)h8[2] * w0.z + (float)h8[3] * w0.w
                  + (float)h8[4] * w1.x + (float)h8[5] * w1.y + (float)h8[6] * w1.z + (float)h8[7] * w1.w;
        }
        part[q][lane] = accE;
        __syncthreads();
        if (tid < 128) {
            const int os = tid >> 6, bb = tid & 63;
            const int oo = bid * 2 + os;
            const float v = part[os][bb] + part[os + 2][bb] + part[os + 4][bb] + part[os + 6][bb] + by[oo];
            out[bb * NOUT + oo] = v;
        }
    }
}

extern "C" void kernel_launch(void* const* d_in, const int* in_sizes, int n_in,
                              void* d_out, int out_size, void* d_ws, size_t ws_size,
                              hipStream_t stream)
{
    const float* x    = (const float*)d_in[0];
    const float* Wih0 = (const float*)d_in[1];
    const float* Whh0 = (const float*)d_in[2];
    const float* bih0 = (const float*)d_in[3];
    const float* bhh0 = (const float*)d_in[4];
    const float* Wih1 = (const float*)d_in[5];
    const float* Whh1 = (const float*)d_in[6];
    const float* bih1 = (const float*)d_in[7];
    const float* bhh1 = (const float*)d_in[8];
    const float* Wy   = (const float*)d_in[9];
    const float* by   = (const float*)d_in[10];
    float* out = (float*)d_out;
    uint4* ws  = (uint4*)d_ws;

    (void)in_sizes; (void)n_in; (void)out_size; (void)ws_size;

    void* args[] = { (void*)&x, (void*)&Wih0, (void*)&Whh0, (void*)&bih0, (void*)&bhh0,
                     (void*)&Wih1, (void*)&Whh1, (void*)&bih1, (void*)&bhh1,
                     (void*)&Wy, (void*)&by, (void*)&out, (void*)&ws };
    hipLaunchCooperativeKernel((const void*)lstm_mfma, dim3(64), dim3(512),
                               args, 0, stream);
}

// Round 5
// 10842.648 us; speedup vs baseline: 3.4687x; 1.6048x over previous
//
#include <hip/hip_runtime.h>
#include <math.h>

typedef _Float16 f16x8 __attribute__((ext_vector_type(8)));
typedef float    f32x4 __attribute__((ext_vector_type(4)));

#define SEQ   512
#define NB    64
#define DIN   256
#define HID   512
#define NOUT  128

#define L0_NKS 24            // K = 256 (x) + 512 (h0) = 768 -> 24 k-slices of 32
#define L1_NKS 32            // K = 512 (h0) + 512 (h1) = 1024 -> 32 k-slices
#define L0_FRAGS (128 * L0_NKS)   // 3072 A-fragments (128 g-tiles)
#define L1_FRAGS (128 * L1_NKS)   // 4096
#define WA_U4 ((L0_FRAGS + L1_FRAGS) * 64)   // uint4 count of packed-weight area
#define G_U4  4096           // one h-buffer parity: [64 k8][64 b] uint4 (fp16x8) = 64KB

#define NBLK  64             // main grid blocks

union U4H8 { uint4 u; f16x8 h; };

__device__ __forceinline__ f16x8 asH(uint4 v) { U4H8 c; c.u = v; return c.h; }

__device__ __forceinline__ f16x8 pack8(float4 a, float4 b) {
    f16x8 r;
    r[0] = (_Float16)a.x; r[1] = (_Float16)a.y; r[2] = (_Float16)a.z; r[3] = (_Float16)a.w;
    r[4] = (_Float16)b.x; r[5] = (_Float16)b.y; r[6] = (_Float16)b.z; r[7] = (_Float16)b.w;
    return r;
}

// ---- lightweight agent-scope grid barrier (no cg, no s_sleep backoff) ----
// release: leader's RELEASE fetch_add publishes this block's h-stores (agent scope).
// acquire: every thread executes an agent-scope acquire fence before reading fresh h.
__device__ __forceinline__ void grid_barrier(unsigned* cnt, unsigned* epoch,
                                             unsigned e, int tid)
{
    __syncthreads();   // all waves' h-stores issued; release below orders them
    if (tid == 0) {
        unsigned old = __hip_atomic_fetch_add(cnt, 1u, __ATOMIC_RELEASE,
                                              __HIP_MEMORY_SCOPE_AGENT);
        if (old == e * NBLK - 1u) {
            __hip_atomic_store(epoch, e, __ATOMIC_RELEASE, __HIP_MEMORY_SCOPE_AGENT);
        } else {
            while (__hip_atomic_load(epoch, __ATOMIC_RELAXED,
                                     __HIP_MEMORY_SCOPE_AGENT) < e) { }
        }
    }
    __syncthreads();
    __builtin_amdgcn_fence(__ATOMIC_ACQUIRE, "agent");   // invalidate stale L1/L2 lines
}

// Persistent-weight sequential loop. Wave q (of 8): type = q&3 (i,f,g,o), btg = q>>2.
template<int LAYER>
__device__ __forceinline__ void run_loop(
    const float* __restrict__ x, const float* __restrict__ bi, const float* __restrict__ bh,
    const uint4* __restrict__ WA, uint4* __restrict__ G0, uint4* __restrict__ G1,
    float (*gsum)[64], _Float16 (*hstage)[64],
    unsigned* cnt, unsigned* epoch,
    int u, int lane, int q, int tid)
{
    constexpr int NKS = LAYER ? L1_NKS : L0_NKS;
    const int typ = q & 3, btg = q >> 2;
    const int gt  = typ * 32 + u;                      // global 16-gate tile index
    const long fbase = LAYER ? (long)L0_FRAGS + (long)gt * L1_NKS : (long)gt * L0_NKS;

    // ---- persistent A fragments (weights) in registers ----
    f16x8 A[NKS];
#pragma unroll
    for (int ks = 0; ks < NKS; ++ks) A[ks] = asH(WA[(fbase + ks) * 64 + lane]);

    // ---- bias (per-lane 4 rows of this wave's D tiles) ----
    const int g0r = typ * 512 + u * 16 + ((lane >> 4) << 2);
    f32x4 bias4;
    {
        const float4 a = *(const float4*)&bi[g0r];
        const float4 b = *(const float4*)&bh[g0r];
        bias4[0] = a.x + b.x; bias4[1] = a.y + b.y; bias4[2] = a.z + b.z; bias4[3] = a.w + b.w;
    }

    const int ju = q, bb = lane;   // pointwise: units ju, ju+8 for batch bb
    float cA = 0.f, cB = 0.f;

    for (int it = 0; it <= SEQ; ++it) {
        const bool active = LAYER ? (it >= 1) : (it < SEQ);
        const int t = LAYER ? it - 1 : it;
        if (active) {
            const uint4* srcRec = (LAYER ? G1 : G0) + G_U4 * ((t + 1) & 1);  // own h[t-1]
            const uint4* srcIn  = LAYER ? (G0 + G_U4 * (t & 1)) : nullptr;   // h0[t]

            // 4 accumulator chains: 2 b-tiles x K-alternation
            f32x4 a0a = {0,0,0,0}, a0b = {0,0,0,0}, a1a = {0,0,0,0}, a1b = {0,0,0,0};
#pragma unroll
            for (int ks = 0; ks < NKS; ++ks) {
                f16x8 B0, B1;
                if (LAYER == 0 && ks < 8) {
                    const int k8 = ks * 4 + (lane >> 4);
                    const int b0 = btg * 32 + (lane & 15);
                    const float* xp0 = x + (size_t)b0 * (SEQ * DIN) + (size_t)t * DIN + k8 * 8;
                    const float* xp1 = xp0 + (size_t)16 * (SEQ * DIN);
                    B0 = pack8(*(const float4*)xp0, *(const float4*)(xp0 + 4));
                    B1 = pack8(*(const float4*)xp1, *(const float4*)(xp1 + 4));
                } else {
                    const uint4* Gs; int k8;
                    if (LAYER == 1) {
                        if (ks < 16) { Gs = srcIn;  k8 = ks * 4 + (lane >> 4); }
                        else         { Gs = srcRec; k8 = (ks - 16) * 4 + (lane >> 4); }
                    } else {
                        Gs = srcRec; k8 = (ks - 8) * 4 + (lane >> 4);
                    }
                    B0 = asH(Gs[k8 * 64 + btg * 32 + (lane & 15)]);
                    B1 = asH(Gs[k8 * 64 + btg * 32 + 16 + (lane & 15)]);
                }
                if (ks & 1) {
                    a0b = __builtin_amdgcn_mfma_f32_16x16x32_f16(A[ks], B0, a0b, 0, 0, 0);
                    a1b = __builtin_amdgcn_mfma_f32_16x16x32_f16(A[ks], B1, a1b, 0, 0, 0);
                } else {
                    a0a = __builtin_amdgcn_mfma_f32_16x16x32_f16(A[ks], B0, a0a, 0, 0, 0);
                    a1a = __builtin_amdgcn_mfma_f32_16x16x32_f16(A[ks], B1, a1a, 0, 0, 0);
                }
            }
            const int gl   = typ * 16 + ((lane >> 4) << 2);
            const int bcol = btg * 32 + (lane & 15);
#pragma unroll
            for (int r = 0; r < 4; ++r) {
                gsum[gl + r][bcol]      = a0a[r] + a0b[r] + bias4[r];
                gsum[gl + r][bcol + 16] = a1a[r] + a1b[r] + bias4[r];
            }
        }
        __syncthreads();
        if (active) {
            // unit ju
            {
                const float gi = gsum[ju][bb],      gf = gsum[16 + ju][bb];
                const float gc = gsum[32 + ju][bb], go = gsum[48 + ju][bb];
                const float i_ = 1.f / (1.f + __expf(-gi));
                const float f_ = 1.f / (1.f + __expf(-gf));
                const float g_ = tanhf(gc);
                const float o_ = 1.f / (1.f + __expf(-go));
                cA = f_ * cA + i_ * g_;
                hstage[ju][bb] = (_Float16)(o_ * tanhf(cA));
            }
            // unit ju+8
            {
                const float gi = gsum[ju + 8][bb],      gf = gsum[16 + ju + 8][bb];
                const float gc = gsum[32 + ju + 8][bb], go = gsum[48 + ju + 8][bb];
                const float i_ = 1.f / (1.f + __expf(-gi));
                const float f_ = 1.f / (1.f + __expf(-gf));
                const float g_ = tanhf(gc);
                const float o_ = 1.f / (1.f + __expf(-go));
                cB = f_ * cB + i_ * g_;
                hstage[ju + 8][bb] = (_Float16)(o_ * tanhf(cB));
            }
        }
        __syncthreads();
        if (active && tid < 128) {
            // coalesced h write-back: 128 x uint4 covers this block's 16 units
            uint4* Gw = (LAYER ? G1 : G0) + G_U4 * (t & 1);
            const int k8l = tid >> 6, b = tid & 63;
            f16x8 v;
#pragma unroll
            for (int e2 = 0; e2 < 8; ++e2) v[e2] = hstage[k8l * 8 + e2][b];
            U4H8 c; c.h = v;
            Gw[(u * 2 + k8l) * 64 + b] = c.u;
        }
        grid_barrier(cnt, epoch, (unsigned)(it + 1), tid);
    }
}

__global__ void __launch_bounds__(512, 2)
lstm_mfma(const float* __restrict__ x,
          const float* __restrict__ bih0, const float* __restrict__ bhh0,
          const float* __restrict__ bih1, const float* __restrict__ bhh1,
          const float* __restrict__ Wy,  const float* __restrict__ by,
          float* __restrict__ out, uint4* __restrict__ ws)
{
    const int bid  = blockIdx.x;     // 0..63
    const int tid  = threadIdx.x;    // 0..511
    const int lane = tid & 63;
    const int q    = tid >> 6;       // wave 0..7
    const int layer = bid >> 5;
    const int u     = bid & 31;      // 16-unit group within layer

    uint4* WA = ws;
    uint4* G0 = ws + WA_U4;              // [2][4096] uint4  (h0 parities)
    uint4* G1 = G0 + 2 * G_U4;           // [2][4096] uint4  (h1 parities)
    unsigned* flags = (unsigned*)(G1 + 2 * G_U4);   // [0]=cnt, [32]=epoch

    __shared__ float    gsum[64][64];
    __shared__ _Float16 hstage[16][64];
    __shared__ float    part[8][64];

    if (layer == 0) run_loop<0>(x, bih0, bhh0, WA, G0, G1, gsum, hstage,
                                flags, flags + 32, u, lane, q, tid);
    else            run_loop<1>(x, bih1, bhh1, WA, G0, G1, gsum, hstage,
                                flags, flags + 32, u, lane, q, tid);

    // ---------- fused output projection ----------
    // h2_final = h1[511], parity 1. out[b][o] = h2 . Wy[o] + by[o]
    {
        const uint4* Hf = G1 + G_U4;           // parity 1
        const int osel = q & 1, kq = q >> 1;   // 4-way K split across waves
        const int o = bid * 2 + osel;
        float accE = 0.f;
#pragma unroll
        for (int i = 0; i < 16; ++i) {
            const int k8 = kq * 16 + i;
            const f16x8 h8 = asH(Hf[k8 * 64 + lane]);
            const float4 w0 = *(const float4*)&Wy[(size_t)o * HID + k8 * 8];
            const float4 w1 = *(const float4*)&Wy[(size_t)o * HID + k8 * 8 + 4];
            accE += (float)h8[0] * w0.x + (float)h8[1] * w0.y + (float)h8[2] * w0.z + (float)h8[3] * w0.w
                  + (float)h8[4] * w1.x + (float)h8[5] * w1.y + (float)h8[6] * w1.z + (float)h8[7] * w1.w;
        }
        part[q][lane] = accE;
        __syncthreads();
        if (tid < 128) {
            const int os = tid >> 6, bb2 = tid & 63;
            const int oo = bid * 2 + os;
            const float v = part[os][bb2] + part[os + 2][bb2] + part[os + 4][bb2] + part[os + 6][bb2] + by[oo];
            out[bb2 * NOUT + oo] = v;
        }
    }
}

// ---------- init kernel: pack weights, zero initial h, reset barrier flags ----------
__global__ void lstm_init(const float* __restrict__ Wih0, const float* __restrict__ Whh0,
                          const float* __restrict__ Wih1, const float* __restrict__ Whh1,
                          uint4* __restrict__ ws)
{
    uint4* WA = ws;
    uint4* G0 = ws + WA_U4;
    uint4* G1 = G0 + 2 * G_U4;
    unsigned* flags = (unsigned*)(G1 + 2 * G_U4);

    const int gtid = blockIdx.x * blockDim.x + threadIdx.x;
    const int nthr = gridDim.x * blockDim.x;

    for (int task = gtid; task < (L0_FRAGS + L1_FRAGS) * 64; task += nthr) {
        const int f = task >> 6, l = task & 63;
        int g, k;
        const float* src;
        if (f < L0_FRAGS) {
            const int gt = f / L0_NKS;
            const int ks = f - gt * L0_NKS;
            g = gt * 16 + (l & 15);
            k = ks * 32 + (l >> 4) * 8;
            src = (k < DIN) ? (Wih0 + (size_t)g * DIN + k)
                            : (Whh0 + (size_t)g * HID + (k - DIN));
        } else {
            const int f1 = f - L0_FRAGS;
            const int gt = f1 >> 5;
            const int ks = f1 & 31;
            g = gt * 16 + (l & 15);
            k = ks * 32 + (l >> 4) * 8;
            src = (k < HID) ? (Wih1 + (size_t)g * HID + k)
                            : (Whh1 + (size_t)g * HID + (k - HID));
        }
        U4H8 c;
        c.h = pack8(*(const float4*)src, *(const float4*)(src + 4));
        WA[task] = c.u;
    }
    // zero parity-1 h buffers (initial state), reset flags
    const uint4 z = make_uint4(0u, 0u, 0u, 0u);
    for (int i = gtid; i < 2 * G_U4; i += nthr) {
        if (i < G_U4) G0[G_U4 + i] = z;
        else          G1[G_U4 + (i - G_U4)] = z;
    }
    if (gtid < 64) flags[gtid] = 0u;
}

extern "C" void kernel_launch(void* const* d_in, const int* in_sizes, int n_in,
                              void* d_out, int out_size, void* d_ws, size_t ws_size,
                              hipStream_t stream)
{
    const float* x    = (const float*)d_in[0];
    const float* Wih0 = (const float*)d_in[1];
    const float* Whh0 = (const float*)d_in[2];
    const float* bih0 = (const float*)d_in[3];
    const float* bhh0 = (const float*)d_in[4];
    const float* Wih1 = (const float*)d_in[5];
    const float* Whh1 = (const float*)d_in[6];
    const float* bih1 = (const float*)d_in[7];
    const float* bhh1 = (const float*)d_in[8];
    const float* Wy   = (const float*)d_in[9];
    const float* by   = (const float*)d_in[10];
    float* out = (float*)d_out;
    uint4* ws  = (uint4*)d_ws;

    (void)in_sizes; (void)n_in; (void)out_size; (void)ws_size;

    hipLaunchKernelGGL(lstm_init, dim3(256), dim3(256), 0, stream,
                       Wih0, Whh0, Wih1, Whh1, ws);

    void* args[] = { (void*)&x, (void*)&bih0, (void*)&bhh0,
                     (void*)&bih1, (void*)&bhh1,
                     (void*)&Wy, (void*)&by, (void*)&out, (void*)&ws };
    (void)hipLaunchCooperativeKernel((const void*)lstm_mfma, dim3(NBLK), dim3(512),
                                     args, 0, stream);
}

// Round 7
// 8977.219 us; speedup vs baseline: 4.1895x; 1.2078x over previous
//
#include <hip/hip_runtime.h>
#include <math.h>

typedef _Float16 f16x8 __attribute__((ext_vector_type(8)));
typedef float    f32x4 __attribute__((ext_vector_type(4)));

#define SEQ   512
#define NB    64
#define DIN   256
#define HID   512
#define NOUT  128

#define L0_NKS 24            // K = 256 (x) + 512 (h0) = 768 -> 24 k-slices of 32
#define L1_NKS 32            // K = 512 (h0) + 512 (h1) = 1024 -> 32 k-slices
#define L0_FRAGS (128 * L0_NKS)   // 3072 A-fragments (128 g-tiles)
#define L1_FRAGS (128 * L1_NKS)   // 4096
#define WA_U4 ((L0_FRAGS + L1_FRAGS) * 64)   // uint4 count of packed-weight area
#define G_U4  4096           // one h-buffer parity: [64 k8][64 b] uint4 (fp16x8) = 64KB

#define NBLK  64             // main grid blocks
#define FLAG_STRIDE 32       // 128B between per-block flags

union U4H8 { uint4 u; f16x8 h; };

__device__ __forceinline__ f16x8 asH(uint4 v) { U4H8 c; c.u = v; return c.h; }

__device__ __forceinline__ f16x8 pack8(float4 a, float4 b) {
    f16x8 r;
    r[0] = (_Float16)a.x; r[1] = (_Float16)a.y; r[2] = (_Float16)a.z; r[3] = (_Float16)a.w;
    r[4] = (_Float16)b.x; r[5] = (_Float16)b.y; r[6] = (_Float16)b.z; r[7] = (_Float16)b.w;
    return r;
}

// ---- flat parallel grid barrier: no RMW, no central counter ----
// arrive: leader release-stores epoch to its OWN flag line (64 parallel stores).
// wait:   wave 0 polls all 64 flags, one per lane; exec-mask divergence means the
//         wave proceeds only when every lane's flag reached e. Then acquire fence.
__device__ __forceinline__ void grid_barrier(unsigned* flags, unsigned e,
                                             int bid, int tid)
{
    __syncthreads();   // drains vmcnt -> this block's h-stores are in L2
    if (tid == 0)
        __hip_atomic_store(&flags[bid * FLAG_STRIDE], e, __ATOMIC_RELEASE,
                           __HIP_MEMORY_SCOPE_AGENT);
    if (tid < 64) {
        while (__hip_atomic_load(&flags[tid * FLAG_STRIDE], __ATOMIC_RELAXED,
                                 __HIP_MEMORY_SCOPE_AGENT) < e)
            __builtin_amdgcn_s_sleep(1);
    }
    __syncthreads();
    __builtin_amdgcn_fence(__ATOMIC_ACQUIRE, "agent");   // invalidate stale L1/L2
}

// Persistent-weight sequential loop. Wave q (of 8): type = q&3 (i,f,g,o), btg = q>>2.
template<int LAYER>
__device__ __forceinline__ void run_loop(
    const float* __restrict__ x, const float* __restrict__ bi, const float* __restrict__ bh,
    const uint4* __restrict__ WA, uint4* __restrict__ G0, uint4* __restrict__ G1,
    float (*gsum)[64], _Float16 (*hstage)[64],
    unsigned* flags, int bid, int u, int lane, int q, int tid)
{
    constexpr int NKS = LAYER ? L1_NKS : L0_NKS;
    const int typ = q & 3, btg = q >> 2;
    const int gt  = typ * 32 + u;                      // global 16-gate tile index
    const long fbase = LAYER ? (long)L0_FRAGS + (long)gt * L1_NKS : (long)gt * L0_NKS;

    // ---- persistent A fragments (weights) in registers ----
    f16x8 A[NKS];
#pragma unroll
    for (int ks = 0; ks < NKS; ++ks) A[ks] = asH(WA[(fbase + ks) * 64 + lane]);

    // ---- bias (per-lane 4 rows of this wave's D tiles) ----
    const int g0r = typ * 512 + u * 16 + ((lane >> 4) << 2);
    f32x4 bias4;
    {
        const float4 a = *(const float4*)&bi[g0r];
        const float4 b = *(const float4*)&bh[g0r];
        bias4[0] = a.x + b.x; bias4[1] = a.y + b.y; bias4[2] = a.z + b.z; bias4[3] = a.w + b.w;
    }

    const int ju = q, bb = lane;   // pointwise: units ju, ju+8 for batch bb
    float cA = 0.f, cB = 0.f;

    // ---- layer-0: x fragments for the CURRENT step, prefetched into regs ----
    f16x8 xB0[8], xB1[8];
    if (LAYER == 0) {
#pragma unroll
        for (int ks = 0; ks < 8; ++ks) {
            const int k8 = ks * 4 + (lane >> 4);
            const int b0 = btg * 32 + (lane & 15);
            const float* xp0 = x + (size_t)b0 * (SEQ * DIN) + k8 * 8;
            const float* xp1 = xp0 + (size_t)16 * (SEQ * DIN);
            xB0[ks] = pack8(*(const float4*)xp0, *(const float4*)(xp0 + 4));
            xB1[ks] = pack8(*(const float4*)xp1, *(const float4*)(xp1 + 4));
        }
    }

    for (int it = 0; it <= SEQ; ++it) {
        const bool active = LAYER ? (it >= 1) : (it < SEQ);
        const int t = LAYER ? it - 1 : it;
        if (active) {
            const uint4* srcRec = (LAYER ? G1 : G0) + G_U4 * ((t + 1) & 1);  // own h[t-1]
            const uint4* srcIn  = LAYER ? (G0 + G_U4 * (t & 1)) : nullptr;   // h0[t]

            // 4 accumulator chains: 2 b-tiles x K-alternation
            f32x4 a0a = {0,0,0,0}, a0b = {0,0,0,0}, a1a = {0,0,0,0}, a1b = {0,0,0,0};
#pragma unroll
            for (int ks = 0; ks < NKS; ++ks) {
                f16x8 B0, B1;
                if (LAYER == 0 && ks < 8) {
                    B0 = xB0[ks];
                    B1 = xB1[ks];
                } else {
                    const uint4* Gs; int k8;
                    if (LAYER == 1) {
                        if (ks < 16) { Gs = srcIn;  k8 = ks * 4 + (lane >> 4); }
                        else         { Gs = srcRec; k8 = (ks - 16) * 4 + (lane >> 4); }
                    } else {
                        Gs = srcRec; k8 = (ks - 8) * 4 + (lane >> 4);
                    }
                    B0 = asH(Gs[k8 * 64 + btg * 32 + (lane & 15)]);
                    B1 = asH(Gs[k8 * 64 + btg * 32 + 16 + (lane & 15)]);
                }
                if (ks & 1) {
                    a0b = __builtin_amdgcn_mfma_f32_16x16x32_f16(A[ks], B0, a0b, 0, 0, 0);
                    a1b = __builtin_amdgcn_mfma_f32_16x16x32_f16(A[ks], B1, a1b, 0, 0, 0);
                } else {
                    a0a = __builtin_amdgcn_mfma_f32_16x16x32_f16(A[ks], B0, a0a, 0, 0, 0);
                    a1a = __builtin_amdgcn_mfma_f32_16x16x32_f16(A[ks], B1, a1a, 0, 0, 0);
                }
            }
            const int gl   = typ * 16 + ((lane >> 4) << 2);
            const int bcol = btg * 32 + (lane & 15);
#pragma unroll
            for (int r = 0; r < 4; ++r) {
                gsum[gl + r][bcol]      = a0a[r] + a0b[r] + bias4[r];
                gsum[gl + r][bcol + 16] = a1a[r] + a1b[r] + bias4[r];
            }
        }
        __syncthreads();
        if (active) {
            // unit ju
            {
                const float gi = gsum[ju][bb],      gf = gsum[16 + ju][bb];
                const float gc = gsum[32 + ju][bb], go = gsum[48 + ju][bb];
                const float i_ = 1.f / (1.f + __expf(-gi));
                const float f_ = 1.f / (1.f + __expf(-gf));
                const float g_ = tanhf(gc);
                const float o_ = 1.f / (1.f + __expf(-go));
                cA = f_ * cA + i_ * g_;
                hstage[ju][bb] = (_Float16)(o_ * tanhf(cA));
            }
            // unit ju+8
            {
                const float gi = gsum[ju + 8][bb],      gf = gsum[16 + ju + 8][bb];
                const float gc = gsum[32 + ju + 8][bb], go = gsum[48 + ju + 8][bb];
                const float i_ = 1.f / (1.f + __expf(-gi));
                const float f_ = 1.f / (1.f + __expf(-gf));
                const float g_ = tanhf(gc);
                const float o_ = 1.f / (1.f + __expf(-go));
                cB = f_ * cB + i_ * g_;
                hstage[ju + 8][bb] = (_Float16)(o_ * tanhf(cB));
            }
        }
        __syncthreads();
        if (active && tid < 128) {
            // coalesced h write-back: 128 x uint4 covers this block's 16 units
            uint4* Gw = (LAYER ? G1 : G0) + G_U4 * (t & 1);
            const int k8l = tid >> 6, b = tid & 63;
            f16x8 v;
#pragma unroll
            for (int e2 = 0; e2 < 8; ++e2) v[e2] = hstage[k8l * 8 + e2][b];
            U4H8 c; c.h = v;
            Gw[(u * 2 + k8l) * 64 + b] = c.u;
        }
        // ---- prefetch next step's x BEFORE the barrier (independent of h) ----
        if (LAYER == 0 && it + 1 < SEQ) {
#pragma unroll
            for (int ks = 0; ks < 8; ++ks) {
                const int k8 = ks * 4 + (lane >> 4);
                const int b0 = btg * 32 + (lane & 15);
                const float* xp0 = x + (size_t)b0 * (SEQ * DIN)
                                     + (size_t)(it + 1) * DIN + k8 * 8;
                const float* xp1 = xp0 + (size_t)16 * (SEQ * DIN);
                xB0[ks] = pack8(*(const float4*)xp0, *(const float4*)(xp0 + 4));
                xB1[ks] = pack8(*(const float4*)xp1, *(const float4*)(xp1 + 4));
            }
        }
        grid_barrier(flags, (unsigned)(it + 1), bid, tid);
    }
}

__global__ void __launch_bounds__(512, 2)
lstm_mfma(const float* __restrict__ x,
          const float* __restrict__ bih0, const float* __restrict__ bhh0,
          const float* __restrict__ bih1, const float* __restrict__ bhh1,
          const float* __restrict__ Wy,  const float* __restrict__ by,
          float* __restrict__ out, uint4* __restrict__ ws)
{
    const int bid  = blockIdx.x;     // 0..63
    const int tid  = threadIdx.x;    // 0..511
    const int lane = tid & 63;
    const int q    = tid >> 6;       // wave 0..7
    const int layer = bid >> 5;
    const int u     = bid & 31;      // 16-unit group within layer

    uint4* WA = ws;
    uint4* G0 = ws + WA_U4;              // [2][4096] uint4  (h0 parities)
    uint4* G1 = G0 + 2 * G_U4;           // [2][4096] uint4  (h1 parities)
    unsigned* flags = (unsigned*)(G1 + 2 * G_U4);   // 64 flags, 128B apart

    __shared__ float    gsum[64][64];
    __shared__ _Float16 hstage[16][64];
    __shared__ float    part[8][64];

    if (layer == 0) run_loop<0>(x, bih0, bhh0, WA, G0, G1, gsum, hstage,
                                flags, bid, u, lane, q, tid);
    else            run_loop<1>(x, bih1, bhh1, WA, G0, G1, gsum, hstage,
                                flags, bid, u, lane, q, tid);

    // ---------- fused output projection ----------
    // h2_final = h1[511], parity 1. out[b][o] = h2 . Wy[o] + by[o]
    {
        const uint4* Hf = G1 + G_U4;           // parity 1
        const int osel = q & 1, kq = q >> 1;   // 4-way K split across waves
        const int o = bid * 2 + osel;
        float accE = 0.f;
#pragma unroll
        for (int i = 0; i < 16; ++i) {
            const int k8 = kq * 16 + i;
            const f16x8 h8 = asH(Hf[k8 * 64 + lane]);
            const float4 w0 = *(const float4*)&Wy[(size_t)o * HID + k8 * 8];
            const float4 w1 = *(const float4*)&Wy[(size_t)o * HID + k8 * 8 + 4];
            accE += (float)h8[0] * w0.x + (float)h8[1] * w0.y + (float)h8[2] * w0.z + (float)h8[3] * w0.w
                  + (float)h8[4] * w1.x + (float)h8[5] * w1.y + (float)h8[6] * w1.z + (float)h8[7] * w1.w;
        }
        part[q][lane] = accE;
        __syncthreads();
        if (tid < 128) {
            const int os = tid >> 6, bb2 = tid & 63;
            const int oo = bid * 2 + os;
            const float v = part[os][bb2] + part[os + 2][bb2] + part[os + 4][bb2] + part[os + 6][bb2] + by[oo];
            out[bb2 * NOUT + oo] = v;
        }
    }
}

// ---------- init kernel: pack weights, zero initial h, reset barrier flags ----------
__global__ void lstm_init(const float* __restrict__ Wih0, const float* __restrict__ Whh0,
                          const float* __restrict__ Wih1, const float* __restrict__ Whh1,
                          uint4* __restrict__ ws)
{
    uint4* WA = ws;
    uint4* G0 = ws + WA_U4;
    uint4* G1 = G0 + 2 * G_U4;
    unsigned* flags = (unsigned*)(G1 + 2 * G_U4);

    const int gtid = blockIdx.x * blockDim.x + threadIdx.x;
    const int nthr = gridDim.x * blockDim.x;

    for (int task = gtid; task < (L0_FRAGS + L1_FRAGS) * 64; task += nthr) {
        const int f = task >> 6, l = task & 63;
        int g, k;
        const float* src;
        if (f < L0_FRAGS) {
            const int gt = f / L0_NKS;
            const int ks = f - gt * L0_NKS;
            g = gt * 16 + (l & 15);
            k = ks * 32 + (l >> 4) * 8;
            src = (k < DIN) ? (Wih0 + (size_t)g * DIN + k)
                            : (Whh0 + (size_t)g * HID + (k - DIN));
        } else {
            const int f1 = f - L0_FRAGS;
            const int gt = f1 >> 5;
            const int ks = f1 & 31;
            g = gt * 16 + (l & 15);
            k = ks * 32 + (l >> 4) * 8;
            src = (k < HID) ? (Wih1 + (size_t)g * HID + k)
                            : (Whh1 + (size_t)g * HID + (k - HID));
        }
        U4H8 c;
        c.h = pack8(*(const float4*)src, *(const float4*)(src + 4));
        WA[task] = c.u;
    }
    // zero parity-1 h buffers (initial state), reset flags
    const uint4 z = make_uint4(0u, 0u, 0u, 0u);
    for (int i = gtid; i < 2 * G_U4; i += nthr) {
        if (i < G_U4) G0[G_U4 + i] = z;
        else          G1[G_U4 + (i - G_U4)] = z;
    }
    for (int i = gtid; i < NBLK * FLAG_STRIDE; i += nthr) flags[i] = 0u;
}

extern "C" void kernel_launch(void* const* d_in, const int* in_sizes, int n_in,
                              void* d_out, int out_size, void* d_ws, size_t ws_size,
                              hipStream_t stream)
{
    const float* x    = (const float*)d_in[0];
    const float* Wih0 = (const float*)d_in[1];
    const float* Whh0 = (const float*)d_in[2];
    const float* bih0 = (const float*)d_in[3];
    const float* bhh0 = (const float*)d_in[4];
    const float* Wih1 = (const float*)d_in[5];
    const float* Whh1 = (const float*)d_in[6];
    const float* bih1 = (const float*)d_in[7];
    const float* bhh1 = (const float*)d_in[8];
    const float* Wy   = (const float*)d_in[9];
    const float* by   = (const float*)d_in[10];
    float* out = (float*)d_out;
    uint4* ws  = (uint4*)d_ws;

    (void)in_sizes; (void)n_in; (void)out_size; (void)ws_size;

    hipLaunchKernelGGL(lstm_init, dim3(256), dim3(256), 0, stream,
                       Wih0, Whh0, Wih1, Whh1, ws);

    void* args[] = { (void*)&x, (void*)&bih0, (void*)&bhh0,
                     (void*)&bih1, (void*)&bhh1,
                     (void*)&Wy, (void*)&by, (void*)&out, (void*)&ws };
    (void)hipLaunchCooperativeKernel((const void*)lstm_mfma, dim3(NBLK), dim3(512),
                                     args, 0, stream);
}

// Round 8
// 6896.443 us; speedup vs baseline: 5.4535x; 1.3017x over previous
//
#include <hip/hip_runtime.h>
#include <math.h>

typedef _Float16 f16x8 __attribute__((ext_vector_type(8)));
typedef float    f32x4 __attribute__((ext_vector_type(4)));
typedef unsigned long long ull;

#define SEQ   512
#define NB    64
#define DIN   256
#define HID   512
#define NOUT  128

#define L0_NKS 24            // K = 256 (x) + 512 (h0) = 768 -> 24 k-slices of 32
#define L1_NKS 32            // K = 512 (h0) + 512 (h1) = 1024 -> 32 k-slices
#define L0_FRAGS (128 * L0_NKS)   // 3072 A-fragments (128 g-tiles)
#define L1_FRAGS (128 * L1_NKS)   // 4096
#define WA_U4 ((L0_FRAGS + L1_FRAGS) * 64)   // uint4 count of packed-weight area
#define G_U4  4096           // one h-buffer parity: [64 k8][64 b] uint4 (fp16x8) = 64KB

#define NBLK  64             // main grid blocks
#define FLAG_STRIDE 32       // 128B between per-block flags

union U4H8 { uint4 u; f16x8 h; };
union U8H8 { ull u[2]; f16x8 h; };

__device__ __forceinline__ f16x8 asH(uint4 v) { U4H8 c; c.u = v; return c.h; }

// h exchange goes through L3 (agent coherence point) via sc1 atomics:
// no L1/L2 line can ever be stale, so NO cache invalidates are needed.
__device__ __forceinline__ f16x8 ldh8_agent(const ull* p) {
    U8H8 c;
    c.u[0] = __hip_atomic_load(p,     __ATOMIC_RELAXED, __HIP_MEMORY_SCOPE_AGENT);
    c.u[1] = __hip_atomic_load(p + 1, __ATOMIC_RELAXED, __HIP_MEMORY_SCOPE_AGENT);
    return c.h;
}
__device__ __forceinline__ void sth8_agent(ull* p, f16x8 v) {
    U8H8 c; c.h = v;
    __hip_atomic_store(p,     c.u[0], __ATOMIC_RELAXED, __HIP_MEMORY_SCOPE_AGENT);
    __hip_atomic_store(p + 1, c.u[1], __ATOMIC_RELAXED, __HIP_MEMORY_SCOPE_AGENT);
}

__device__ __forceinline__ f16x8 pack8(float4 a, float4 b) {
    f16x8 r;
    r[0] = (_Float16)a.x; r[1] = (_Float16)a.y; r[2] = (_Float16)a.z; r[3] = (_Float16)a.w;
    r[4] = (_Float16)b.x; r[5] = (_Float16)b.y; r[6] = (_Float16)b.z; r[7] = (_Float16)b.w;
    return r;
}

// ---- flat parallel grid barrier: no RMW, no fences, no cache invalidates ----
// __syncthreads drains vmcnt(0), so all h sc1-stores are L3-committed before the
// (relaxed) flag store issues. Pollers read flags AND h data straight from L3.
__device__ __forceinline__ void grid_barrier(unsigned* flags, unsigned e,
                                             int bid, int tid)
{
    __syncthreads();   // vmcnt(0): this block's h-stores are committed at L3
    if (tid == 0)
        __hip_atomic_store(&flags[bid * FLAG_STRIDE], e, __ATOMIC_RELAXED,
                           __HIP_MEMORY_SCOPE_AGENT);
    if (tid < 64) {
        while (__hip_atomic_load(&flags[tid * FLAG_STRIDE], __ATOMIC_RELAXED,
                                 __HIP_MEMORY_SCOPE_AGENT) < e)
            __builtin_amdgcn_s_sleep(1);
    }
    __syncthreads();
}

// Persistent-weight sequential loop. Wave q (of 8): type = q&3 (i,f,g,o), btg = q>>2.
template<int LAYER>
__device__ __forceinline__ void run_loop(
    const float* __restrict__ x, const float* __restrict__ bi, const float* __restrict__ bh,
    const uint4* __restrict__ WA, uint4* __restrict__ G0, uint4* __restrict__ G1,
    float (*gsum)[64], _Float16 (*hstage)[64],
    unsigned* flags, int bid, int u, int lane, int q, int tid)
{
    constexpr int NKS = LAYER ? L1_NKS : L0_NKS;
    const int typ = q & 3, btg = q >> 2;
    const int gt  = typ * 32 + u;                      // global 16-gate tile index
    const long fbase = LAYER ? (long)L0_FRAGS + (long)gt * L1_NKS : (long)gt * L0_NKS;

    // ---- persistent A fragments (weights) in registers ----
    f16x8 A[NKS];
#pragma unroll
    for (int ks = 0; ks < NKS; ++ks) A[ks] = asH(WA[(fbase + ks) * 64 + lane]);

    // ---- bias (per-lane 4 rows of this wave's D tiles) ----
    const int g0r = typ * 512 + u * 16 + ((lane >> 4) << 2);
    f32x4 bias4;
    {
        const float4 a = *(const float4*)&bi[g0r];
        const float4 b = *(const float4*)&bh[g0r];
        bias4[0] = a.x + b.x; bias4[1] = a.y + b.y; bias4[2] = a.z + b.z; bias4[3] = a.w + b.w;
    }

    const int ju = q, bb = lane;   // pointwise: units ju, ju+8 for batch bb
    float cA = 0.f, cB = 0.f;

    // ---- layer-0: x fragments for the CURRENT step, prefetched into regs ----
    f16x8 xB0[8], xB1[8];
    if (LAYER == 0) {
#pragma unroll
        for (int ks = 0; ks < 8; ++ks) {
            const int k8 = ks * 4 + (lane >> 4);
            const int b0 = btg * 32 + (lane & 15);
            const float* xp0 = x + (size_t)b0 * (SEQ * DIN) + k8 * 8;
            const float* xp1 = xp0 + (size_t)16 * (SEQ * DIN);
            xB0[ks] = pack8(*(const float4*)xp0, *(const float4*)(xp0 + 4));
            xB1[ks] = pack8(*(const float4*)xp1, *(const float4*)(xp1 + 4));
        }
    }

    for (int it = 0; it <= SEQ; ++it) {
        const bool active = LAYER ? (it >= 1) : (it < SEQ);
        const int t = LAYER ? it - 1 : it;
        if (active) {
            const uint4* srcRec = (LAYER ? G1 : G0) + G_U4 * ((t + 1) & 1);  // own h[t-1]
            const uint4* srcIn  = LAYER ? (G0 + G_U4 * (t & 1)) : nullptr;   // h0[t]

            // 4 accumulator chains: 2 b-tiles x K-alternation
            f32x4 a0a = {0,0,0,0}, a0b = {0,0,0,0}, a1a = {0,0,0,0}, a1b = {0,0,0,0};
#pragma unroll
            for (int ks = 0; ks < NKS; ++ks) {
                f16x8 B0, B1;
                if (LAYER == 0 && ks < 8) {
                    B0 = xB0[ks];
                    B1 = xB1[ks];
                } else {
                    const uint4* Gs; int k8;
                    if (LAYER == 1) {
                        if (ks < 16) { Gs = srcIn;  k8 = ks * 4 + (lane >> 4); }
                        else         { Gs = srcRec; k8 = (ks - 16) * 4 + (lane >> 4); }
                    } else {
                        Gs = srcRec; k8 = (ks - 8) * 4 + (lane >> 4);
                    }
                    const ull* p0 = (const ull*)(Gs + k8 * 64 + btg * 32 + (lane & 15));
                    B0 = ldh8_agent(p0);
                    B1 = ldh8_agent(p0 + 32);   // +16 uint4 = +32 ull
                }
                if (ks & 1) {
                    a0b = __builtin_amdgcn_mfma_f32_16x16x32_f16(A[ks], B0, a0b, 0, 0, 0);
                    a1b = __builtin_amdgcn_mfma_f32_16x16x32_f16(A[ks], B1, a1b, 0, 0, 0);
                } else {
                    a0a = __builtin_amdgcn_mfma_f32_16x16x32_f16(A[ks], B0, a0a, 0, 0, 0);
                    a1a = __builtin_amdgcn_mfma_f32_16x16x32_f16(A[ks], B1, a1a, 0, 0, 0);
                }
            }
            const int gl   = typ * 16 + ((lane >> 4) << 2);
            const int bcol = btg * 32 + (lane & 15);
#pragma unroll
            for (int r = 0; r < 4; ++r) {
                gsum[gl + r][bcol]      = a0a[r] + a0b[r] + bias4[r];
                gsum[gl + r][bcol + 16] = a1a[r] + a1b[r] + bias4[r];
            }
        }
        __syncthreads();
        if (active) {
            // unit ju
            {
                const float gi = gsum[ju][bb],      gf = gsum[16 + ju][bb];
                const float gc = gsum[32 + ju][bb], go = gsum[48 + ju][bb];
                const float i_ = 1.f / (1.f + __expf(-gi));
                const float f_ = 1.f / (1.f + __expf(-gf));
                const float g_ = tanhf(gc);
                const float o_ = 1.f / (1.f + __expf(-go));
                cA = f_ * cA + i_ * g_;
                hstage[ju][bb] = (_Float16)(o_ * tanhf(cA));
            }
            // unit ju+8
            {
                const float gi = gsum[ju + 8][bb],      gf = gsum[16 + ju + 8][bb];
                const float gc = gsum[32 + ju + 8][bb], go = gsum[48 + ju + 8][bb];
                const float i_ = 1.f / (1.f + __expf(-gi));
                const float f_ = 1.f / (1.f + __expf(-gf));
                const float g_ = tanhf(gc);
                const float o_ = 1.f / (1.f + __expf(-go));
                cB = f_ * cB + i_ * g_;
                hstage[ju + 8][bb] = (_Float16)(o_ * tanhf(cB));
            }
        }
        __syncthreads();
        if (active && tid < 128) {
            // coalesced h write-back straight to L3 (sc1): 128 x 16B
            uint4* Gw = (LAYER ? G1 : G0) + G_U4 * (t & 1);
            const int k8l = tid >> 6, b = tid & 63;
            f16x8 v;
#pragma unroll
            for (int e2 = 0; e2 < 8; ++e2) v[e2] = hstage[k8l * 8 + e2][b];
            sth8_agent((ull*)(Gw + (u * 2 + k8l) * 64 + b), v);
        }
        // ---- prefetch next step's x BEFORE the barrier (independent of h) ----
        if (LAYER == 0 && it + 1 < SEQ) {
#pragma unroll
            for (int ks = 0; ks < 8; ++ks) {
                const int k8 = ks * 4 + (lane >> 4);
                const int b0 = btg * 32 + (lane & 15);
                const float* xp0 = x + (size_t)b0 * (SEQ * DIN)
                                     + (size_t)(it + 1) * DIN + k8 * 8;
                const float* xp1 = xp0 + (size_t)16 * (SEQ * DIN);
                xB0[ks] = pack8(*(const float4*)xp0, *(const float4*)(xp0 + 4));
                xB1[ks] = pack8(*(const float4*)xp1, *(const float4*)(xp1 + 4));
            }
        }
        grid_barrier(flags, (unsigned)(it + 1), bid, tid);
    }
}

__global__ void __launch_bounds__(512, 2)
lstm_mfma(const float* __restrict__ x,
          const float* __restrict__ bih0, const float* __restrict__ bhh0,
          const float* __restrict__ bih1, const float* __restrict__ bhh1,
          const float* __restrict__ Wy,  const float* __restrict__ by,
          float* __restrict__ out, uint4* __restrict__ ws)
{
    const int bid  = blockIdx.x;     // 0..63
    const int tid  = threadIdx.x;    // 0..511
    const int lane = tid & 63;
    const int q    = tid >> 6;       // wave 0..7
    const int layer = bid >> 5;
    const int u     = bid & 31;      // 16-unit group within layer

    uint4* WA = ws;
    uint4* G0 = ws + WA_U4;              // [2][4096] uint4  (h0 parities)
    uint4* G1 = G0 + 2 * G_U4;           // [2][4096] uint4  (h1 parities)
    unsigned* flags = (unsigned*)(G1 + 2 * G_U4);   // 64 flags, 128B apart

    __shared__ float    gsum[64][64];
    __shared__ _Float16 hstage[16][64];
    __shared__ float    part[8][64];

    if (layer == 0) run_loop<0>(x, bih0, bhh0, WA, G0, G1, gsum, hstage,
                                flags, bid, u, lane, q, tid);
    else            run_loop<1>(x, bih1, bhh1, WA, G0, G1, gsum, hstage,
                                flags, bid, u, lane, q, tid);

    // ---------- fused output projection ----------
    // h2_final = h1[511], parity 1. out[b][o] = h2 . Wy[o] + by[o]
    {
        const uint4* Hf = G1 + G_U4;           // parity 1
        const int osel = q & 1, kq = q >> 1;   // 4-way K split across waves
        const int o = bid * 2 + osel;
        float accE = 0.f;
#pragma unroll
        for (int i = 0; i < 16; ++i) {
            const int k8 = kq * 16 + i;
            const f16x8 h8 = ldh8_agent((const ull*)(Hf + k8 * 64 + lane));
            const float4 w0 = *(const float4*)&Wy[(size_t)o * HID + k8 * 8];
            const float4 w1 = *(const float4*)&Wy[(size_t)o * HID + k8 * 8 + 4];
            accE += (float)h8[0] * w0.x + (float)h8[1] * w0.y + (float)h8[2] * w0.z + (float)h8[3] * w0.w
                  + (float)h8[4] * w1.x + (float)h8[5] * w1.y + (float)h8[6] * w1.z + (float)h8[7] * w1.w;
        }
        part[q][lane] = accE;
        __syncthreads();
        if (tid < 128) {
            const int os = tid >> 6, bb2 = tid & 63;
            const int oo = bid * 2 + os;
            const float v = part[os][bb2] + part[os + 2][bb2] + part[os + 4][bb2] + part[os + 6][bb2] + by[oo];
            out[bb2 * NOUT + oo] = v;
        }
    }
}

// ---------- init kernel: pack weights, zero initial h, reset barrier flags ----------
// (plain stores are fine: the kernel-boundary release makes them L3-visible
//  before lstm_mfma starts — empirically confirmed by rounds 5/7 passing)
__global__ void lstm_init(const float* __restrict__ Wih0, const float* __restrict__ Whh0,
                          const float* __restrict__ Wih1, const float* __restrict__ Whh1,
                          uint4* __restrict__ ws)
{
    uint4* WA = ws;
    uint4* G0 = ws + WA_U4;
    uint4* G1 = G0 + 2 * G_U4;
    unsigned* flags = (unsigned*)(G1 + 2 * G_U4);

    const int gtid = blockIdx.x * blockDim.x + threadIdx.x;
    const int nthr = gridDim.x * blockDim.x;

    for (int task = gtid; task < (L0_FRAGS + L1_FRAGS) * 64; task += nthr) {
        const int f = task >> 6, l = task & 63;
        int g, k;
        const float* src;
        if (f < L0_FRAGS) {
            const int gt = f / L0_NKS;
            const int ks = f - gt * L0_NKS;
            g = gt * 16 + (l & 15);
            k = ks * 32 + (l >> 4) * 8;
            src = (k < DIN) ? (Wih0 + (size_t)g * DIN + k)
                            : (Whh0 + (size_t)g * HID + (k - DIN));
        } else {
            const int f1 = f - L0_FRAGS;
            const int gt = f1 >> 5;
            const int ks = f1 & 31;
            g = gt * 16 + (l & 15);
            k = ks * 32 + (l >> 4) * 8;
            src = (k < HID) ? (Wih1 + (size_t)g * HID + k)
                            : (Whh1 + (size_t)g * HID + (k - HID));
        }
        U4H8 c;
        c.h = pack8(*(const float4*)src, *(const float4*)(src + 4));
        WA[task] = c.u;
    }
    // zero parity-1 h buffers (initial state), reset flags
    const uint4 z = make_uint4(0u, 0u, 0u, 0u);
    for (int i = gtid; i < 2 * G_U4; i += nthr) {
        if (i < G_U4) G0[G_U4 + i] = z;
        else          G1[G_U4 + (i - G_U4)] = z;
    }
    for (int i = gtid; i < NBLK * FLAG_STRIDE; i += nthr) flags[i] = 0u;
}

extern "C" void kernel_launch(void* const* d_in, const int* in_sizes, int n_in,
                              void* d_out, int out_size, void* d_ws, size_t ws_size,
                              hipStream_t stream)
{
    const float* x    = (const float*)d_in[0];
    const float* Wih0 = (const float*)d_in[1];
    const float* Whh0 = (const float*)d_in[2];
    const float* bih0 = (const float*)d_in[3];
    const float* bhh0 = (const float*)d_in[4];
    const float* Wih1 = (const float*)d_in[5];
    const float* Whh1 = (const float*)d_in[6];
    const float* bih1 = (const float*)d_in[7];
    const float* bhh1 = (const float*)d_in[8];
    const float* Wy   = (const float*)d_in[9];
    const float* by   = (const float*)d_in[10];
    float* out = (float*)d_out;
    uint4* ws  = (uint4*)d_ws;

    (void)in_sizes; (void)n_in; (void)out_size; (void)ws_size;

    hipLaunchKernelGGL(lstm_init, dim3(256), dim3(256), 0, stream,
                       Wih0, Whh0, Wih1, Whh1, ws);

    // 64 blocks on 256 CUs: trivially co-resident; custom barrier needs no
    // cooperative launch.
    hipLaunchKernelGGL(lstm_mfma, dim3(NBLK), dim3(512), 0, stream,
                       x, bih0, bhh0, bih1, bhh1, Wy, by, out, ws);
}